// Round 4
// baseline (1040.830 us; speedup 1.0000x reference)
//
#include <hip/hip_runtime.h>

// Problem constants (from reference): B=16, T=4096, D=256, K=1024
#define N_TOK 65536
#define DIM   256
#define KCODE 1024

// GEMM tile config: 128 tokens x 128 codes per block, 8x8 per-thread micro-tile
#define TM 128
#define TN 128
#define KB 16
#define NTHREADS 256

// fp32 gap below which the top-2 go to fp64 refinement
#define REFINE_EPS 0.125f
// fp64 gap below which the reference's fp32 pipeline likely collapsed the two
// distances onto the same fp32 grid point (ulp at dist~512 is 6.1e-5) ->
// first-occurrence argmin picks the LOWER index.
#define TIE_THETA 1.0e-4

// ws layout (floats):
//   [0]                      loss accum
//   [16 .. 16+1024)          c_sq   (numpy-pairwise-exact)
//   [2048 .. 2048+65536)     x_sq   (numpy-pairwise-exact)
//   [67584 .. +65536)        idx1 (int) fp32 argmin candidate / final index
//   [133120 .. +65536)       idx2 (int) runner-up (-1 if no refine needed)
#define WS_CSQ_OFF  16
#define WS_XSQ_OFF  2048
#define WS_IDX1_OFF (2048 + N_TOK)
#define WS_IDX2_OFF (WS_IDX1_OFF + N_TOK)

__global__ void zero_loss_kernel(float* ws) {
    if (threadIdx.x == 0) ws[0] = 0.0f;
}

// numpy-pairwise-exact row sum-of-squares for [rows, 256] fp32.
// pairwise_sum(a,256) = pw(a,128) + pw(a+128,128); pw(·,128) = 8 accumulators
// r[j] = sum of 16 sequential terms, combined ((r0+r1)+(r2+r3))+((r4+r5)+(r6+r7)).
__global__ void rowsq_np_kernel(const float* __restrict__ m,
                                float* __restrict__ out, int rows) {
#pragma clang fp contract(off)
    int row = blockIdx.x * 16 + (threadIdx.x >> 4);
    int l   = threadIdx.x & 15;
    if (row >= rows) return;
    int h = l >> 3;   // which 128-half
    int j = l & 7;    // accumulator index within half
    const float* p = m + (size_t)row * DIM + h * 128 + j;
    float v = p[0];
    float r = v * v;
#pragma unroll
    for (int i = 1; i < 16; ++i) {
        float w  = p[i * 8];
        float w2 = w * w;
        r = r + w2;
    }
    float t = r + __shfl_xor(r, 1);
    t = t + __shfl_xor(t, 2);
    t = t + __shfl_xor(t, 4);
    t = t + __shfl_xor(t, 8);
    if (l == 0) out[row] = t;
}

// Insert (d, idx) into a sorted top-2 with lower-index tie-break.
__device__ __forceinline__ void ins2(float d, int idx,
                                     float& d1, int& i1, float& d2, int& i2) {
    if (d < d1 || (d == d1 && idx < i1)) {
        d2 = d1; i2 = i1; d1 = d; i1 = idx;
    } else if ((d < d2 || (d == d2 && idx < i2)) && idx != i1) {
        d2 = d; i2 = idx;
    }
}

__launch_bounds__(NTHREADS)
__global__ void vq_main_kernel(const float* __restrict__ x,
                               const float* __restrict__ cb,
                               const float* __restrict__ xsq,
                               const float* __restrict__ csq,
                               int* __restrict__ idx1,
                               int* __restrict__ idx2) {
    // k-major LDS tiles: As[k][token], Bs[k][code]
    __shared__ __align__(16) float As[KB][TM];
    __shared__ __align__(16) float Bs[KB][TN];

    const int tid  = threadIdx.x;
    const int tx   = tid & 15;   // code group (8 codes)
    const int ty   = tid >> 4;   // token group (8 tokens)
    const int tok0 = blockIdx.x * TM;

    // running top-2 (simulated np dist, idx) per owned token
    float gd1[8], gd2[8];
    int   gi1[8], gi2[8];
#pragma unroll
    for (int i = 0; i < 8; ++i) {
        gd1[i] = 3.4e38f; gd2[i] = 3.4e38f;
        gi1[i] = 0x7fffffff; gi2[i] = 0x7fffffff;
    }

    float xs[8];
#pragma unroll
    for (int i = 0; i < 8; ++i) xs[i] = xsq[tok0 + ty * 8 + i];

    for (int cc = 0; cc < KCODE / TN; ++cc) {
        const int code0 = cc * TN;
        float acc[8][8];
#pragma unroll
        for (int i = 0; i < 8; ++i)
#pragma unroll
            for (int j = 0; j < 8; ++j) acc[i][j] = 0.0f;

        // k ascending, single accumulator, sequential fma (BLAS-like)
        for (int kc = 0; kc < DIM / KB; ++kc) {
            const int k0 = kc * KB;
            __syncthreads();
#pragma unroll
            for (int s = 0; s < 2; ++s) {
                int ff = tid * 2 + s;
                int tt = ff >> 2;
                int kq = ff & 3;
                float4 g = *reinterpret_cast<const float4*>(
                    x + (size_t)(tok0 + tt) * DIM + k0 + kq * 4);
                As[kq * 4 + 0][tt] = g.x;
                As[kq * 4 + 1][tt] = g.y;
                As[kq * 4 + 2][tt] = g.z;
                As[kq * 4 + 3][tt] = g.w;
                float4 h = *reinterpret_cast<const float4*>(
                    cb + (size_t)(code0 + tt) * DIM + k0 + kq * 4);
                Bs[kq * 4 + 0][tt] = h.x;
                Bs[kq * 4 + 1][tt] = h.y;
                Bs[kq * 4 + 2][tt] = h.z;
                Bs[kq * 4 + 3][tt] = h.w;
            }
            __syncthreads();

#pragma unroll
            for (int kk = 0; kk < KB; ++kk) {
                float a[8], b[8];
                *reinterpret_cast<float4*>(&a[0]) =
                    *reinterpret_cast<const float4*>(&As[kk][ty * 8]);
                *reinterpret_cast<float4*>(&a[4]) =
                    *reinterpret_cast<const float4*>(&As[kk][ty * 8 + 4]);
                *reinterpret_cast<float4*>(&b[0]) =
                    *reinterpret_cast<const float4*>(&Bs[kk][tx * 8]);
                *reinterpret_cast<float4*>(&b[4]) =
                    *reinterpret_cast<const float4*>(&Bs[kk][tx * 8 + 4]);
#pragma unroll
                for (int i = 0; i < 8; ++i)
#pragma unroll
                    for (int j = 0; j < 8; ++j)
                        acc[i][j] = fmaf(a[i], b[j], acc[i][j]);
            }
        }

        float cs[8];
        *reinterpret_cast<float4*>(&cs[0]) =
            *reinterpret_cast<const float4*>(csq + code0 + tx * 8);
        *reinterpret_cast<float4*>(&cs[4]) =
            *reinterpret_cast<const float4*>(csq + code0 + tx * 8 + 4);

        {
#pragma clang fp contract(off)
#pragma unroll
            for (int i = 0; i < 8; ++i) {
                // local top-2 over my 8 codes (np op order: (x_sq - 2P) + c_sq)
                float l1 = 3.4e38f, l2 = 3.4e38f;
                int   j1 = 0x7fffffff, j2 = 0x7fffffff;
#pragma unroll
                for (int j = 0; j < 8; ++j) {
                    float tw   = 2.0f * acc[i][j];
                    float dist = (xs[i] - tw) + cs[j];
                    ins2(dist, code0 + tx * 8 + j, l1, j1, l2, j2);
                }
                // butterfly across the 16 tx lanes, merging top-2 pairs
#pragma unroll
                for (int m = 1; m < 16; m <<= 1) {
                    float o1 = __shfl_xor(l1, m);
                    int   p1 = __shfl_xor(j1, m);
                    float o2 = __shfl_xor(l2, m);
                    int   p2 = __shfl_xor(j2, m);
                    ins2(o1, p1, l1, j1, l2, j2);
                    ins2(o2, p2, l1, j1, l2, j2);
                }
                ins2(l1, j1, gd1[i], gi1[i], gd2[i], gi2[i]);
                ins2(l2, j2, gd1[i], gi1[i], gd2[i], gi2[i]);
            }
        }
    }

    if (tx == 0) {
#pragma unroll
        for (int i = 0; i < 8; ++i) {
            int t = tok0 + ty * 8 + i;
            idx1[t] = gi1[i];
            idx2[t] = (gd2[i] - gd1[i] < REFINE_EPS) ? gi2[i] : -1;
        }
    }
}

// fp64 refine with collapse-tolerant tie-break: if the TRUE gap is below ~1.6
// ulp of the fp32 dist magnitude, the reference's fp32 pipeline almost surely
// produced an exact fp32 tie -> first-occurrence argmin -> LOWER index.
__global__ void refine_kernel(const float* __restrict__ x,
                              const float* __restrict__ cb,
                              int* __restrict__ idx1,
                              const int* __restrict__ idx2) {
    int t = blockIdx.x * 256 + threadIdx.x;
    if (t >= N_TOK) return;
    int j2 = idx2[t];
    if (j2 < 0) return;
    int j1 = idx1[t];
    const float* xr = x + (size_t)t * DIM;
    const float* c1 = cb + (size_t)j1 * DIM;
    const float* c2 = cb + (size_t)j2 * DIM;
    double sA = 0.0, dA = 0.0, sB = 0.0, dB = 0.0;
    for (int k = 0; k < DIM; ++k) {
        double xv = (double)xr[k];
        double a  = (double)c1[k];
        double b  = (double)c2[k];
        sA += a * a; dA += xv * a;
        sB += b * b; dB += xv * b;
    }
    double DA = sA - 2.0 * dA;   // per-token ||x||^2 offset cancels in the gap
    double DB = sB - 2.0 * dB;
    double gap = DB - DA;
    int pick;
    if (gap > TIE_THETA)        pick = j1;                 // clear fp64 winner
    else if (gap < -TIE_THETA)  pick = j2;
    else                        pick = (j1 < j2) ? j1 : j2; // collapsed tie -> lower idx
    idx1[t] = pick;
}

// Output: quantized rows (exact ref math: x + (q - x)), indices as float,
// and the commitment-loss partial sums.
__launch_bounds__(NTHREADS)
__global__ void output_kernel(const float* __restrict__ x,
                              const float* __restrict__ cb,
                              const int* __restrict__ idx,
                              float* __restrict__ out_q,
                              float* __restrict__ out_idx,
                              float* __restrict__ loss_ws) {
    __shared__ int   sh_idx[TM];
    __shared__ float wsum[4];
    const int tid  = threadIdx.x;
    const int tok0 = blockIdx.x * TM;

    if (tid < TM) sh_idx[tid] = idx[tok0 + tid];
    __syncthreads();

    float lsum = 0.0f;
    for (int t = 0; t < TM; ++t) {
        int code = sh_idx[t];
        float q  = cb[(size_t)code * DIM + tid];
        float xv = x[(size_t)(tok0 + t) * DIM + tid];
        out_q[(size_t)(tok0 + t) * DIM + tid] = xv + (q - xv);
        float df = xv - q;
        lsum = fmaf(df, df, lsum);
    }
    if (tid < TM) out_idx[tok0 + tid] = (float)sh_idx[tid];

#pragma unroll
    for (int off = 1; off < 64; off <<= 1) lsum += __shfl_xor(lsum, off);
    if ((tid & 63) == 0) wsum[tid >> 6] = lsum;
    __syncthreads();
    if (tid == 0) atomicAdd(loss_ws, (wsum[0] + wsum[1]) + (wsum[2] + wsum[3]));
}

__global__ void finalize_kernel(const float* ws, float* out_loss) {
    if (threadIdx.x == 0) out_loss[0] = ws[0] * (1.0f / 16777216.0f); // COMMITMENT * mean
}

extern "C" void kernel_launch(void* const* d_in, const int* in_sizes, int n_in,
                              void* d_out, int out_size, void* d_ws, size_t ws_size,
                              hipStream_t stream) {
    const float* x  = (const float*)d_in[0];   // [16,4096,256] fp32
    const float* cb = (const float*)d_in[1];   // [1024,256] fp32

    float* out      = (float*)d_out;
    float* out_q    = out;                                  // N*D floats
    float* out_idx  = out + (size_t)N_TOK * DIM;            // N floats (indices as fp32)
    float* out_loss = out_idx + N_TOK;                      // 1 float

    float* ws   = (float*)d_ws;
    float* csq  = ws + WS_CSQ_OFF;
    float* xsq  = ws + WS_XSQ_OFF;
    int*   idx1 = (int*)(ws + WS_IDX1_OFF);
    int*   idx2 = (int*)(ws + WS_IDX2_OFF);

    zero_loss_kernel<<<1, 64, 0, stream>>>(ws);
    rowsq_np_kernel<<<N_TOK / 16, 256, 0, stream>>>(x, xsq, N_TOK);
    rowsq_np_kernel<<<KCODE / 16, 256, 0, stream>>>(cb, csq, KCODE);
    vq_main_kernel<<<N_TOK / TM, NTHREADS, 0, stream>>>(x, cb, xsq, csq, idx1, idx2);
    refine_kernel<<<N_TOK / 256, 256, 0, stream>>>(x, cb, idx1, idx2);
    output_kernel<<<N_TOK / TM, NTHREADS, 0, stream>>>(x, cb, idx1, out_q, out_idx, ws);
    finalize_kernel<<<1, 64, 0, stream>>>(ws, out_loss);
}

// Round 5
// 1002.701 us; speedup vs baseline: 1.0380x; 1.0380x over previous
//
#include <hip/hip_runtime.h>

// Problem constants (from reference): B=16, T=4096, D=256, K=1024
#define N_TOK 65536
#define DIM   256
#define KCODE 1024

// GEMM tile config: 128 tokens x 128 codes per chunk, 8x8 per-thread micro-tile.
// Each block handles 512 codes (one half of the codebook) -> grid 1024 = 4 blocks/CU.
#define TM 128
#define TN 128
#define KB 16
#define NTHREADS 256
#define HALF_CODES 512

// fp32 gap below which the top-2 go to fp64 refinement
#define REFINE_EPS 0.125f
// fp64 gap below which the reference's fp32 pipeline likely collapsed the two
// distances onto the same fp32 grid point -> first-occurrence -> LOWER index.
#define TIE_THETA 1.0e-4

// ws layout (floats):
//   [0]                       loss accum
//   [16 .. 16+1024)           c_sq   (numpy-pairwise-exact)
//   [2048 .. 2048+65536)      x_sq   (numpy-pairwise-exact)
//   [67584 .. +65536)         idx (int) final argmin
//   [133120 .. +4*2*65536)    pairs (float4): per (token, half) {d1, d2, i1, i2}
#define WS_CSQ_OFF   16
#define WS_XSQ_OFF   2048
#define WS_IDX_OFF   (2048 + N_TOK)
#define WS_PAIRS_OFF (WS_IDX_OFF + N_TOK)

__global__ void zero_loss_kernel(float* ws) {
    if (threadIdx.x == 0) ws[0] = 0.0f;
}

// numpy-pairwise-exact row sum-of-squares for [rows, 256] fp32.
__global__ void rowsq_np_kernel(const float* __restrict__ m,
                                float* __restrict__ out, int rows) {
#pragma clang fp contract(off)
    int row = blockIdx.x * 16 + (threadIdx.x >> 4);
    int l   = threadIdx.x & 15;
    if (row >= rows) return;
    int h = l >> 3;
    int j = l & 7;
    const float* p = m + (size_t)row * DIM + h * 128 + j;
    float v = p[0];
    float r = v * v;
#pragma unroll
    for (int i = 1; i < 16; ++i) {
        float w  = p[i * 8];
        float w2 = w * w;
        r = r + w2;
    }
    float t = r + __shfl_xor(r, 1);
    t = t + __shfl_xor(t, 2);
    t = t + __shfl_xor(t, 4);
    t = t + __shfl_xor(t, 8);
    if (l == 0) out[row] = t;
}

// Insert (d, idx) into a sorted top-2 with lower-index tie-break.
__device__ __forceinline__ void ins2(float d, int idx,
                                     float& d1, int& i1, float& d2, int& i2) {
    if (d < d1 || (d == d1 && idx < i1)) {
        d2 = d1; i2 = i1; d1 = d; i1 = idx;
    } else if ((d < d2 || (d == d2 && idx < i2)) && idx != i1) {
        d2 = d; i2 = idx;
    }
}

__launch_bounds__(NTHREADS)
__global__ void vq_main_kernel(const float* __restrict__ x,
                               const float* __restrict__ cb,
                               const float* __restrict__ xsq,
                               const float* __restrict__ csq,
                               float4* __restrict__ pairs) {
    // k-major LDS tiles: As[k][token], Bs[k][code]
    __shared__ __align__(16) float As[KB][TM];
    __shared__ __align__(16) float Bs[KB][TN];

    const int tid  = threadIdx.x;
    const int tx   = tid & 15;        // code group
    const int ty   = tid >> 4;        // token group (8 tokens)
    const int bx   = blockIdx.x;
    const int half = bx & 1;          // which 512-code half
    const int tok0 = (bx >> 1) * TM;

    // running top-2 (simulated np dist, idx) per owned token, over this half
    float gd1[8], gd2[8];
    int   gi1[8], gi2[8];
#pragma unroll
    for (int i = 0; i < 8; ++i) {
        gd1[i] = 3.4e38f; gd2[i] = 3.4e38f;
        gi1[i] = 0x7fffffff; gi2[i] = 0x7fffffff;
    }

    float xs[8];
#pragma unroll
    for (int i = 0; i < 8; ++i) xs[i] = xsq[tok0 + ty * 8 + i];

    for (int cc = 0; cc < HALF_CODES / TN; ++cc) {
        const int code0 = half * HALF_CODES + cc * TN;
        float acc[8][8];
#pragma unroll
        for (int i = 0; i < 8; ++i)
#pragma unroll
            for (int j = 0; j < 8; ++j) acc[i][j] = 0.0f;

        // k ascending, single accumulator, sequential fma (np/BLAS-matching order)
        for (int kc = 0; kc < DIM / KB; ++kc) {
            const int k0 = kc * KB;
            __syncthreads();
#pragma unroll
            for (int s = 0; s < 2; ++s) {
                int ff = tid * 2 + s;
                int tt = ff >> 2;
                int kq = ff & 3;
                float4 g = *reinterpret_cast<const float4*>(
                    x + (size_t)(tok0 + tt) * DIM + k0 + kq * 4);
                As[kq * 4 + 0][tt] = g.x;
                As[kq * 4 + 1][tt] = g.y;
                As[kq * 4 + 2][tt] = g.z;
                As[kq * 4 + 3][tt] = g.w;
                float4 h = *reinterpret_cast<const float4*>(
                    cb + (size_t)(code0 + tt) * DIM + k0 + kq * 4);
                Bs[kq * 4 + 0][tt] = h.x;
                Bs[kq * 4 + 1][tt] = h.y;
                Bs[kq * 4 + 2][tt] = h.z;
                Bs[kq * 4 + 3][tt] = h.w;
            }
            __syncthreads();

#pragma unroll
            for (int kk = 0; kk < KB; ++kk) {
                float a[8], b[8];
                *reinterpret_cast<float4*>(&a[0]) =
                    *reinterpret_cast<const float4*>(&As[kk][ty * 8]);
                *reinterpret_cast<float4*>(&a[4]) =
                    *reinterpret_cast<const float4*>(&As[kk][ty * 8 + 4]);
                // 4+4 split code ownership: read offsets tx*4 and 64+tx*4 ->
                // banks {0,4,...,28} x2 = 2-way aliasing = conflict-free.
                *reinterpret_cast<float4*>(&b[0]) =
                    *reinterpret_cast<const float4*>(&Bs[kk][tx * 4]);
                *reinterpret_cast<float4*>(&b[4]) =
                    *reinterpret_cast<const float4*>(&Bs[kk][64 + tx * 4]);
#pragma unroll
                for (int i = 0; i < 8; ++i)
#pragma unroll
                    for (int j = 0; j < 8; ++j)
                        acc[i][j] = fmaf(a[i], b[j], acc[i][j]);
            }
        }

        // c_sq for my 8 codes (4+4 split)
        float cs[8];
        *reinterpret_cast<float4*>(&cs[0]) =
            *reinterpret_cast<const float4*>(csq + code0 + tx * 4);
        *reinterpret_cast<float4*>(&cs[4]) =
            *reinterpret_cast<const float4*>(csq + code0 + 64 + tx * 4);

        {
#pragma clang fp contract(off)
#pragma unroll
            for (int i = 0; i < 8; ++i) {
                float l1 = 3.4e38f, l2 = 3.4e38f;
                int   j1 = 0x7fffffff, j2 = 0x7fffffff;
#pragma unroll
                for (int j = 0; j < 8; ++j) {
                    float tw   = 2.0f * acc[i][j];
                    float dist = (xs[i] - tw) + cs[j];
                    int   cidx = code0 + ((j < 4) ? (tx * 4 + j) : (64 + tx * 4 + j - 4));
                    ins2(dist, cidx, l1, j1, l2, j2);
                }
#pragma unroll
                for (int m = 1; m < 16; m <<= 1) {
                    float o1 = __shfl_xor(l1, m);
                    int   p1 = __shfl_xor(j1, m);
                    float o2 = __shfl_xor(l2, m);
                    int   p2 = __shfl_xor(j2, m);
                    ins2(o1, p1, l1, j1, l2, j2);
                    ins2(o2, p2, l1, j1, l2, j2);
                }
                ins2(l1, j1, gd1[i], gi1[i], gd2[i], gi2[i]);
                ins2(l2, j2, gd1[i], gi1[i], gd2[i], gi2[i]);
            }
        }
    }

    if (tx == 0) {
#pragma unroll
        for (int i = 0; i < 8; ++i) {
            int t = tok0 + ty * 8 + i;
            float4 pr;
            pr.x = gd1[i];
            pr.y = gd2[i];
            pr.z = __int_as_float(gi1[i]);
            pr.w = __int_as_float(gi2[i]);
            pairs[(size_t)t * 2 + half] = pr;
        }
    }
}

// Merge the two code-half top-2 pairs, then fp64-refine near-ties with the
// collapse-tolerant tie-break (proven in R4).
__global__ void merge_refine_kernel(const float* __restrict__ x,
                                    const float* __restrict__ cb,
                                    const float4* __restrict__ pairs,
                                    int* __restrict__ idx_out) {
    int t = blockIdx.x * 256 + threadIdx.x;
    if (t >= N_TOK) return;
    float4 pa = pairs[(size_t)t * 2 + 0];
    float4 pb = pairs[(size_t)t * 2 + 1];
    float d1 = pa.x, d2 = pa.y;
    int   i1 = __float_as_int(pa.z), i2 = __float_as_int(pa.w);
    ins2(pb.x, __float_as_int(pb.z), d1, i1, d2, i2);
    ins2(pb.y, __float_as_int(pb.w), d1, i1, d2, i2);

    int pick = i1;
    if (d2 - d1 < REFINE_EPS) {
        const float* xr = x + (size_t)t * DIM;
        const float* c1 = cb + (size_t)i1 * DIM;
        const float* c2 = cb + (size_t)i2 * DIM;
        double sA = 0.0, dA = 0.0, sB = 0.0, dB = 0.0;
        for (int k = 0; k < DIM; ++k) {
            double xv = (double)xr[k];
            double a  = (double)c1[k];
            double b  = (double)c2[k];
            sA += a * a; dA += xv * a;
            sB += b * b; dB += xv * b;
        }
        double DA  = sA - 2.0 * dA;
        double DB  = sB - 2.0 * dB;
        double gap = DB - DA;
        if (gap > TIE_THETA)       pick = i1;
        else if (gap < -TIE_THETA) pick = i2;
        else                       pick = (i1 < i2) ? i1 : i2;
    }
    idx_out[t] = pick;
}

// Output: quantized rows (exact ref math: x + (q - x)), indices as float,
// and the commitment-loss partial sums.
__launch_bounds__(NTHREADS)
__global__ void output_kernel(const float* __restrict__ x,
                              const float* __restrict__ cb,
                              const int* __restrict__ idx,
                              float* __restrict__ out_q,
                              float* __restrict__ out_idx,
                              float* __restrict__ loss_ws) {
    __shared__ int   sh_idx[TM];
    __shared__ float wsum[4];
    const int tid  = threadIdx.x;
    const int tok0 = blockIdx.x * TM;

    if (tid < TM) sh_idx[tid] = idx[tok0 + tid];
    __syncthreads();

    float lsum = 0.0f;
    for (int t = 0; t < TM; ++t) {
        int code = sh_idx[t];
        float q  = cb[(size_t)code * DIM + tid];
        float xv = x[(size_t)(tok0 + t) * DIM + tid];
        out_q[(size_t)(tok0 + t) * DIM + tid] = xv + (q - xv);
        float df = xv - q;
        lsum = fmaf(df, df, lsum);
    }
    if (tid < TM) out_idx[tok0 + tid] = (float)sh_idx[tid];

#pragma unroll
    for (int off = 1; off < 64; off <<= 1) lsum += __shfl_xor(lsum, off);
    if ((tid & 63) == 0) wsum[tid >> 6] = lsum;
    __syncthreads();
    if (tid == 0) atomicAdd(loss_ws, (wsum[0] + wsum[1]) + (wsum[2] + wsum[3]));
}

__global__ void finalize_kernel(const float* ws, float* out_loss) {
    if (threadIdx.x == 0) out_loss[0] = ws[0] * (1.0f / 16777216.0f); // COMMITMENT * mean
}

extern "C" void kernel_launch(void* const* d_in, const int* in_sizes, int n_in,
                              void* d_out, int out_size, void* d_ws, size_t ws_size,
                              hipStream_t stream) {
    const float* x  = (const float*)d_in[0];   // [16,4096,256] fp32
    const float* cb = (const float*)d_in[1];   // [1024,256] fp32

    float* out      = (float*)d_out;
    float* out_q    = out;
    float* out_idx  = out + (size_t)N_TOK * DIM;
    float* out_loss = out_idx + N_TOK;

    float*  ws    = (float*)d_ws;
    float*  csq   = ws + WS_CSQ_OFF;
    float*  xsq   = ws + WS_XSQ_OFF;
    int*    idx   = (int*)(ws + WS_IDX_OFF);
    float4* pairs = (float4*)(ws + WS_PAIRS_OFF);

    zero_loss_kernel<<<1, 64, 0, stream>>>(ws);
    rowsq_np_kernel<<<N_TOK / 16, 256, 0, stream>>>(x, xsq, N_TOK);
    rowsq_np_kernel<<<KCODE / 16, 256, 0, stream>>>(cb, csq, KCODE);
    vq_main_kernel<<<(N_TOK / TM) * 2, NTHREADS, 0, stream>>>(x, cb, xsq, csq, pairs);
    merge_refine_kernel<<<N_TOK / 256, 256, 0, stream>>>(x, cb, pairs, idx);
    output_kernel<<<N_TOK / TM, NTHREADS, 0, stream>>>(x, cb, idx, out_q, out_idx, ws);
    finalize_kernel<<<1, 64, 0, stream>>>(ws, out_loss);
}